// Round 18
// baseline (452.961 us; speedup 1.0000x reference)
//
#include <hip/hip_runtime.h>
#include <hip/hip_bf16.h>

#define NROWS 16384
#define DIM   256
#define SEGS  16
#define BN    64                      // staged tile: 64 cols x 256 k (fp8) = 16 KB
#define NT    ((NROWS / SEGS) / BN)   // 16 tiles per segment
#define INVT  14.285714285714286f
#define C1f   20.60992915555662f      // log2(e)/0.07 ; A is pre-scaled by this
#define LN2f  0.6931471805599453f

typedef __attribute__((ext_vector_type(8)))  int   int8v;    // fp8 A/B fragment (32 bytes)
typedef __attribute__((ext_vector_type(16))) float f32x16;   // 32x32 MFMA accumulator

#define SCALE1 0x7F7F7F7F   // E8M0 = 1.0 in every byte (opsel-proof)

// Kernel 1: L2-normalize (fp32); emit fp8 e4m3 A (row-major, xC1) and fp8 B in the
// LINEAR DMA staging layout, plus exact fp32 diagonal. One wave per row.
// B layout (16B chunks): chunk(col,kcb) = (col>>6)*1024 + kcb*64 + (col&63)
__global__ __launch_bounds__(256) void norm_diag_kernel(
    const float* __restrict__ fl, const float* __restrict__ fg,
    unsigned char* __restrict__ A, unsigned char* __restrict__ B,
    float* __restrict__ diag, float* __restrict__ out)
{
    int tid  = threadIdx.x;
    int wave = tid >> 6, lane = tid & 63;
    int row  = blockIdx.x * 4 + wave;
    if (blockIdx.x == 0 && tid == 0) out[0] = 0.0f;   // zero accumulator for final atomicAdd

    float4 xl = ((const float4*)(fl + (size_t)row * DIM))[lane];
    float4 xg = ((const float4*)(fg + (size_t)row * DIM))[lane];
    float ssl = xl.x*xl.x + xl.y*xl.y + xl.z*xl.z + xl.w*xl.w;
    float ssg = xg.x*xg.x + xg.y*xg.y + xg.z*xg.z + xg.w*xg.w;
    for (int m = 1; m < 64; m <<= 1) {
        ssl += __shfl_xor(ssl, m, 64);
        ssg += __shfl_xor(ssg, m, 64);
    }
    float il = 1.0f / fmaxf(sqrtf(ssl), 1e-12f);
    float ig = 1.0f / fmaxf(sqrtf(ssg), 1e-12f);
    float nl0 = xl.x*il, nl1 = xl.y*il, nl2 = xl.z*il, nl3 = xl.w*il;
    float ng0 = xg.x*ig, ng1 = xg.y*ig, ng2 = xg.z*ig, ng3 = xg.w*ig;

    int pa = __builtin_amdgcn_cvt_pk_fp8_f32(nl0 * C1f, nl1 * C1f, 0, false);
    pa     = __builtin_amdgcn_cvt_pk_fp8_f32(nl2 * C1f, nl3 * C1f, pa, true);
    int pb = __builtin_amdgcn_cvt_pk_fp8_f32(ng0, ng1, 0, false);
    pb     = __builtin_amdgcn_cvt_pk_fp8_f32(ng2, ng3, pb, true);
    ((int*)(A + (size_t)row * DIM))[lane] = pa;   // A row-major

    {   // B in linear staging layout
        int kcb = lane >> 2;          // 16B chunk along K (0..15)
        int b4  = lane & 3;           // dword within chunk
        unsigned chunk = (unsigned)((row >> 6) * 1024 + kcb * 64 + (row & 63));
        ((int*)B)[chunk * 4 + b4] = pb;
    }

    float d = nl0*ng0 + nl1*ng1 + nl2*ng2 + nl3*ng3;   // exact fp32 diagonal
    for (int m = 1; m < 64; m <<= 1) d += __shfl_xor(d, m, 64);
    if (lane == 0) diag[row] = d;
}

// Kernel 2: fused sim-GEMM + fixed-max sumexp, MX-fp8 32x32x64.
// R15 per-wave structure (VGPR=120, proven spill-free) at DOUBLED occupancy:
// BN=64 (32 KB LDS dbuf) + SEGS=16 (grid 1024) -> 4 blocks/CU = 4 waves/SIMD.
// Four independent waves per SIMD in arbitrary phases give the scheduler a
// natural MFMA/VALU/LDS mix (the overlap R15's stagger couldn't create).
__global__ __launch_bounds__(256, 4) void sim_lse_kernel(
    const unsigned char* __restrict__ A, const unsigned char* __restrict__ B,
    float* __restrict__ lpart)
{
    __shared__ __align__(16) unsigned char bt[2 * BN * DIM];   // 2 x 16 KB double buffer

    int tid  = threadIdx.x;
    int lane = tid & 63;
    int l31  = lane & 31, half = lane >> 5;
    int wave = tid >> 6;
    int seg  = blockIdx.x;
    int rowBase = blockIdx.y * 256 + wave * 64;

    unsigned vb = (unsigned)(l31 * 16 + half * 2048);   // LDS read base

    // Preload A fragments: lane(l31,half) holds A[m=l31][k = kk*64 + half*32 + 0..31]
    int8v af[2][4];
#pragma unroll
    for (int s = 0; s < 2; ++s) {
        const unsigned char* ap = A + (size_t)(rowBase + s*32 + l31) * DIM + half * 32;
#pragma unroll
        for (int kk = 0; kk < 4; ++kk) {
            int4 lo = *(const int4*)(ap + kk * 64);
            int4 hi = *(const int4*)(ap + kk * 64 + 16);
            int8v v;
            v[0]=lo.x; v[1]=lo.y; v[2]=lo.z; v[3]=lo.w;
            v[4]=hi.x; v[5]=hi.y; v[6]=hi.z; v[7]=hi.w;
            af[s][kk] = v;
        }
    }

    f32x16 lv[2];
    f32x16 Z;
    f32x16 accA[2], accB[2];
#pragma unroll
    for (int r = 0; r < 16; ++r) {
        lv[0][r] = -1.0f; lv[1][r] = -1.0f;   // compensate the one dummy epilogue
        Z[r] = 0.0f;
        accB[0][r] = 0.0f; accB[1][r] = 0.0f; // dummy-epilogue source
    }

    int T0 = seg * NT;

    // Stage one 16 KB tile (1024 chunks): thread moves 4 chunks
    auto stage = [&](int T, unsigned bufo) {
        const unsigned char* g = B + (size_t)T * (BN * DIM) + (wave * 256 + lane) * 16;
        unsigned lo = bufo + (unsigned)(wave * 256) * 16;
#pragma unroll
        for (int j = 0; j < 4; ++j) {
            __builtin_amdgcn_global_load_lds(
                (const __attribute__((address_space(1))) unsigned int*)(g + j * 1024),
                (__attribute__((address_space(3))) unsigned int*)&bt[lo + j * 1024],
                16, 0, 0);
        }
    };

    // 8 ds_read_b128 (imm offsets) + 8 MFMAs for one 64x32 unit
    auto chain = [&](f32x16 (&ac)[2], unsigned ab, unsigned offc) {
        int8v bf[4];
#pragma unroll
        for (int kk = 0; kk < 4; ++kk) {
            int4 lo = *(const int4*)&bt[ab + offc + (unsigned)kk * 4096u];
            int4 hi = *(const int4*)&bt[ab + offc + (unsigned)kk * 4096u + 1024u];
            int8v v;
            v[0]=lo.x; v[1]=lo.y; v[2]=lo.z; v[3]=lo.w;
            v[4]=hi.x; v[5]=hi.y; v[6]=hi.z; v[7]=hi.w;
            bf[kk] = v;
        }
        ac[0] = __builtin_amdgcn_mfma_scale_f32_32x32x64_f8f6f4(
            af[0][0], bf[0], Z, 0, 0, 0, SCALE1, 0, SCALE1);
        ac[1] = __builtin_amdgcn_mfma_scale_f32_32x32x64_f8f6f4(
            af[1][0], bf[0], Z, 0, 0, 0, SCALE1, 0, SCALE1);
#pragma unroll
        for (int kk = 1; kk < 4; ++kk) {
            ac[0] = __builtin_amdgcn_mfma_scale_f32_32x32x64_f8f6f4(
                af[0][kk], bf[kk], ac[0], 0, 0, 0, SCALE1, 0, SCALE1);
            ac[1] = __builtin_amdgcn_mfma_scale_f32_32x32x64_f8f6f4(
                af[1][kk], bf[kk], ac[1], 0, 0, 0, SCALE1, 0, SCALE1);
        }
    };

    auto epi = [&](f32x16 (&ac)[2]) {
#pragma unroll
        for (int s = 0; s < 2; ++s) {
            f32x16 e;
#pragma unroll
            for (int r = 0; r < 16; ++r)
                e[r] = __builtin_amdgcn_exp2f(ac[s][r]);
            lv[s] += e;
        }
    };

    stage(T0, 0);

    for (int t = 0; t < NT; ++t) {
        unsigned bufo = (t & 1) ? (unsigned)(BN * DIM) : 0u;
        __syncthreads();   // drains own tile-t DMA (in flight a full tile), syncs waves

        if (t + 1 < NT)
            stage(T0 + t + 1, (t & 1) ? 0u : (unsigned)(BN * DIM));

        unsigned ab = vb + bufo;
        chain(accA, ab, 0u);    epi(accB);   // cols 0-31
        chain(accB, ab, 512u);  epi(accA);   // cols 32-63
    }
    epi(accB);   // final unit

    // Sum across the 32 column-lanes
#pragma unroll
    for (int s = 0; s < 2; ++s)
#pragma unroll
        for (int r = 0; r < 16; ++r) {
            float v = lv[s][r];
            v += __shfl_xor(v, 1, 64);
            v += __shfl_xor(v, 2, 64);
            v += __shfl_xor(v, 4, 64);
            v += __shfl_xor(v, 8, 64);
            v += __shfl_xor(v, 16, 64);
            lv[s][r] = v;
        }
    if (l31 == 0) {
#pragma unroll
        for (int s = 0; s < 2; ++s)
#pragma unroll
            for (int r = 0; r < 16; ++r) {
                int row = rowBase + s*32 + (r & 3) + 8*(r >> 2) + 4*half;
                lpart[(size_t)seg * NROWS + row] = lv[s][r];
            }
    }
}

// Kernel 3: loss_i = -invT*diag_i + ln2*log2(sum_seg l_part), then mean via atomicAdd.
__global__ __launch_bounds__(256) void reduce_kernel(
    const float* __restrict__ lpart, const float* __restrict__ diag,
    float* __restrict__ out)
{
    __shared__ float sm[4];
    int gtid = blockIdx.x * 256 + threadIdx.x;
    float s = 0.0f;
    for (int row = gtid; row < NROWS; row += 32 * 256) {
        float t = 0.0f;
#pragma unroll
        for (int g = 0; g < SEGS; ++g) t += lpart[(size_t)g * NROWS + row];
        s += LN2f * log2f(t) - INVT * diag[row];
    }
    for (int m = 1; m < 64; m <<= 1) s += __shfl_xor(s, m, 64);
    int wave = threadIdx.x >> 6, lane = threadIdx.x & 63;
    if (lane == 0) sm[wave] = s;
    __syncthreads();
    if (threadIdx.x == 0) {
        float tot = sm[0] + sm[1] + sm[2] + sm[3];
        atomicAdd(out, tot * (1.0f / NROWS));
    }
}

extern "C" void kernel_launch(void* const* d_in, const int* in_sizes, int n_in,
                              void* d_out, int out_size, void* d_ws, size_t ws_size,
                              hipStream_t stream) {
    const float* fl = (const float*)d_in[0];
    const float* fg = (const float*)d_in[1];
    float* out = (float*)d_out;

    char* ws = (char*)d_ws;
    unsigned char* A = (unsigned char*)ws;                         // 16384*256 = 4 MB
    unsigned char* B = A + (size_t)NROWS * DIM;                    // 4 MB (staging layout)
    float* diag  = (float*)(ws + 2 * (size_t)NROWS * DIM);         // 64 KB
    float* lpart = diag + NROWS;                                   // SEGS*N*4 = 1 MB

    norm_diag_kernel<<<NROWS / 4, 256, 0, stream>>>(fl, fg, A, B, diag, out);
    sim_lse_kernel<<<dim3(SEGS, NROWS / 256), 256, 0, stream>>>(A, B, lpart);
    reduce_kernel<<<32, 256, 0, stream>>>(lpart, diag, out);
}

// Round 19
// 137.934 us; speedup vs baseline: 3.2839x; 3.2839x over previous
//
#include <hip/hip_runtime.h>
#include <hip/hip_bf16.h>

#define NROWS 16384
#define DIM   256
#define SEGS  8
#define BN    128                     // staged tile: 128 cols x 256 k (fp8) = 32 KB
#define NT    ((NROWS / SEGS) / BN)   // 16 tiles per segment
#define INVT  14.285714285714286f
#define C1f   20.60992915555662f      // log2(e)/0.07 ; A is pre-scaled by this
#define LN2f  0.6931471805599453f

typedef __attribute__((ext_vector_type(8)))  int   int8v;    // fp8 A/B fragment (32 bytes)
typedef __attribute__((ext_vector_type(16))) float f32x16;   // 32x32 MFMA accumulator

#define SCALE1 0x7F7F7F7F   // E8M0 = 1.0 in every byte (opsel-proof)

// Kernel 1: L2-normalize (fp32); emit fp8 e4m3 A (row-major, xC1) and fp8 B in the
// LINEAR DMA staging layout, plus exact fp32 diagonal. One wave per row.
// B layout (16B chunks): chunk(col,kcb) = (col>>7)*2048 + ((col>>6)&1)*1024
//                                        + kcb*64 + (col&63)
__global__ __launch_bounds__(256) void norm_diag_kernel(
    const float* __restrict__ fl, const float* __restrict__ fg,
    unsigned char* __restrict__ A, unsigned char* __restrict__ B,
    float* __restrict__ diag, float* __restrict__ out)
{
    int tid  = threadIdx.x;
    int wave = tid >> 6, lane = tid & 63;
    int row  = blockIdx.x * 4 + wave;
    if (blockIdx.x == 0 && tid == 0) out[0] = 0.0f;   // zero accumulator for final atomicAdd

    float4 xl = ((const float4*)(fl + (size_t)row * DIM))[lane];
    float4 xg = ((const float4*)(fg + (size_t)row * DIM))[lane];
    float ssl = xl.x*xl.x + xl.y*xl.y + xl.z*xl.z + xl.w*xl.w;
    float ssg = xg.x*xg.x + xg.y*xg.y + xg.z*xg.z + xg.w*xg.w;
    for (int m = 1; m < 64; m <<= 1) {
        ssl += __shfl_xor(ssl, m, 64);
        ssg += __shfl_xor(ssg, m, 64);
    }
    float il = 1.0f / fmaxf(sqrtf(ssl), 1e-12f);
    float ig = 1.0f / fmaxf(sqrtf(ssg), 1e-12f);
    float nl0 = xl.x*il, nl1 = xl.y*il, nl2 = xl.z*il, nl3 = xl.w*il;
    float ng0 = xg.x*ig, ng1 = xg.y*ig, ng2 = xg.z*ig, ng3 = xg.w*ig;

    int pa = __builtin_amdgcn_cvt_pk_fp8_f32(nl0 * C1f, nl1 * C1f, 0, false);
    pa     = __builtin_amdgcn_cvt_pk_fp8_f32(nl2 * C1f, nl3 * C1f, pa, true);
    int pb = __builtin_amdgcn_cvt_pk_fp8_f32(ng0, ng1, 0, false);
    pb     = __builtin_amdgcn_cvt_pk_fp8_f32(ng2, ng3, pb, true);
    ((int*)(A + (size_t)row * DIM))[lane] = pa;   // A row-major

    {   // B in linear staging layout
        int kcb = lane >> 2;          // 16B chunk along K (0..15)
        int b4  = lane & 3;           // dword within chunk
        unsigned chunk = (unsigned)((row >> 7) * 2048 + ((row >> 6) & 1) * 1024
                                    + kcb * 64 + (row & 63));
        ((int*)B)[chunk * 4 + b4] = pb;
    }

    float d = nl0*ng0 + nl1*ng1 + nl2*ng2 + nl3*ng3;   // exact fp32 diagonal
    for (int m = 1; m < 64; m <<= 1) d += __shfl_xor(d, m, 64);
    if (lane == 0) diag[row] = d;
}

// Kernel 2: fused sim-GEMM + fixed-max sumexp, MX-fp8 32x32x64.
// R15 base (DMA prefetch, one barrier/tile, ping-pong acc, deferred epilogue,
// imm-offset LDS reads; 68.6 us, VGPR 120 spill-free) with fragment loads
// rewritten as direct 16B stores into the int8v tuple halves -- ds_read_b128
// lands straight in the MFMA operand registers, killing the v_mov repack chains.
__global__ __launch_bounds__(256, 2) void sim_lse_kernel(
    const unsigned char* __restrict__ A, const unsigned char* __restrict__ B,
    float* __restrict__ lpart)
{
    __shared__ __align__(16) unsigned char bt[2 * BN * DIM];   // 2 x 32 KB double buffer

    int tid  = threadIdx.x;
    int lane = tid & 63;
    int l31  = lane & 31, half = lane >> 5;
    int wave = tid >> 6;
    int seg  = blockIdx.x;
    int rowBase = blockIdx.y * 256 + wave * 64;

    unsigned vb = (unsigned)(l31 * 16 + half * 2048);   // LDS read base

    // Preload A fragments: direct 16B loads into tuple halves (no repack movs)
    int8v af[2][4];
#pragma unroll
    for (int s = 0; s < 2; ++s) {
        const unsigned char* ap = A + (size_t)(rowBase + s*32 + l31) * DIM + half * 32;
#pragma unroll
        for (int kk = 0; kk < 4; ++kk) {
            ((int4*)&af[s][kk])[0] = *(const int4*)(ap + kk * 64);
            ((int4*)&af[s][kk])[1] = *(const int4*)(ap + kk * 64 + 16);
        }
    }

    f32x16 lv[2];
    f32x16 Z;
    f32x16 accA[2], accB[2];
#pragma unroll
    for (int r = 0; r < 16; ++r) {
        lv[0][r] = -1.0f; lv[1][r] = -1.0f;   // compensate the one dummy epilogue
        Z[r] = 0.0f;
        accB[0][r] = 0.0f; accB[1][r] = 0.0f; // dummy-epilogue source
    }

    int T0 = seg * NT;

    auto stage = [&](int T, unsigned bufo) {
        const unsigned char* g = B + (size_t)T * (BN * DIM) + (wave * 512 + lane) * 16;
        unsigned lo = bufo + (unsigned)(wave * 512) * 16;
#pragma unroll
        for (int j = 0; j < 8; ++j) {
            __builtin_amdgcn_global_load_lds(
                (const __attribute__((address_space(1))) unsigned int*)(g + j * 1024),
                (__attribute__((address_space(3))) unsigned int*)&bt[lo + j * 1024],
                16, 0, 0);
        }
    };

    // 8 ds_read_b128 directly into int8v halves + 8 MFMAs for one 64x32 unit
    auto chain = [&](f32x16 (&ac)[2], unsigned ab, unsigned offc) {
        int8v bf[4];
#pragma unroll
        for (int kk = 0; kk < 4; ++kk) {
            ((int4*)&bf[kk])[0] = *(const int4*)&bt[ab + offc + (unsigned)kk * 4096u];
            ((int4*)&bf[kk])[1] = *(const int4*)&bt[ab + offc + (unsigned)kk * 4096u + 1024u];
        }
        ac[0] = __builtin_amdgcn_mfma_scale_f32_32x32x64_f8f6f4(
            af[0][0], bf[0], Z, 0, 0, 0, SCALE1, 0, SCALE1);
        ac[1] = __builtin_amdgcn_mfma_scale_f32_32x32x64_f8f6f4(
            af[1][0], bf[0], Z, 0, 0, 0, SCALE1, 0, SCALE1);
#pragma unroll
        for (int kk = 1; kk < 4; ++kk) {
            ac[0] = __builtin_amdgcn_mfma_scale_f32_32x32x64_f8f6f4(
                af[0][kk], bf[kk], ac[0], 0, 0, 0, SCALE1, 0, SCALE1);
            ac[1] = __builtin_amdgcn_mfma_scale_f32_32x32x64_f8f6f4(
                af[1][kk], bf[kk], ac[1], 0, 0, 0, SCALE1, 0, SCALE1);
        }
    };

    auto epi = [&](f32x16 (&ac)[2]) {
#pragma unroll
        for (int s = 0; s < 2; ++s) {
            f32x16 e;
#pragma unroll
            for (int r = 0; r < 16; ++r)
                e[r] = __builtin_amdgcn_exp2f(ac[s][r]);
            lv[s] += e;
        }
    };

    stage(T0, 0);

    for (int t = 0; t < NT; ++t) {
        unsigned bufo = (t & 1) ? (unsigned)(BN * DIM) : 0u;
        __syncthreads();   // drains own tile-t DMA (in flight a full tile), syncs waves

        if (t + 1 < NT)
            stage(T0 + t + 1, (t & 1) ? 0u : (unsigned)(BN * DIM));

        unsigned ab = vb + bufo;
        chain(accA, ab, 0u);      epi(accB);
        chain(accB, ab, 512u);    epi(accA);
        chain(accA, ab, 16384u);  epi(accB);
        chain(accB, ab, 16896u);  epi(accA);
    }
    epi(accB);   // final unit

    // Sum across the 32 column-lanes
#pragma unroll
    for (int s = 0; s < 2; ++s)
#pragma unroll
        for (int r = 0; r < 16; ++r) {
            float v = lv[s][r];
            v += __shfl_xor(v, 1, 64);
            v += __shfl_xor(v, 2, 64);
            v += __shfl_xor(v, 4, 64);
            v += __shfl_xor(v, 8, 64);
            v += __shfl_xor(v, 16, 64);
            lv[s][r] = v;
        }
    if (l31 == 0) {
#pragma unroll
        for (int s = 0; s < 2; ++s)
#pragma unroll
            for (int r = 0; r < 16; ++r) {
                int row = rowBase + s*32 + (r & 3) + 8*(r >> 2) + 4*half;
                lpart[(size_t)seg * NROWS + row] = lv[s][r];
            }
    }
}

// Kernel 3: loss_i = -invT*diag_i + ln2*log2(sum_seg l_part), then mean via atomicAdd.
__global__ __launch_bounds__(256) void reduce_kernel(
    const float* __restrict__ lpart, const float* __restrict__ diag,
    float* __restrict__ out)
{
    __shared__ float sm[4];
    int gtid = blockIdx.x * 256 + threadIdx.x;
    float s = 0.0f;
    for (int row = gtid; row < NROWS; row += 32 * 256) {
        float t = 0.0f;
#pragma unroll
        for (int g = 0; g < SEGS; ++g) t += lpart[(size_t)g * NROWS + row];
        s += LN2f * log2f(t) - INVT * diag[row];
    }
    for (int m = 1; m < 64; m <<= 1) s += __shfl_xor(s, m, 64);
    int wave = threadIdx.x >> 6, lane = threadIdx.x & 63;
    if (lane == 0) sm[wave] = s;
    __syncthreads();
    if (threadIdx.x == 0) {
        float tot = sm[0] + sm[1] + sm[2] + sm[3];
        atomicAdd(out, tot * (1.0f / NROWS));
    }
}

extern "C" void kernel_launch(void* const* d_in, const int* in_sizes, int n_in,
                              void* d_out, int out_size, void* d_ws, size_t ws_size,
                              hipStream_t stream) {
    const float* fl = (const float*)d_in[0];
    const float* fg = (const float*)d_in[1];
    float* out = (float*)d_out;

    char* ws = (char*)d_ws;
    unsigned char* A = (unsigned char*)ws;                         // 16384*256 = 4 MB
    unsigned char* B = A + (size_t)NROWS * DIM;                    // 4 MB (staging layout)
    float* diag  = (float*)(ws + 2 * (size_t)NROWS * DIM);         // 64 KB
    float* lpart = diag + NROWS;                                   // SEGS*N*4 = 512 KB

    norm_diag_kernel<<<NROWS / 4, 256, 0, stream>>>(fl, fg, A, B, diag, out);
    sim_lse_kernel<<<dim3(SEGS, NROWS / 256), 256, 0, stream>>>(A, B, lpart);
    reduce_kernel<<<32, 256, 0, stream>>>(lpart, diag, out);
}